// Round 3
// baseline (122.356 us; speedup 1.0000x reference)
//
#include <hip/hip_runtime.h>

// GarNet: B=64 V=4096 F=16 A=8 P=16 NF=16. Inputs float32 (runtime-probed,
// confirmed R2), num_vertex int32, OUTPUT float32 (confirmed R2: bf16 writes
// read back as f32 garbage; reference dtype is f32).
//
// Algebraic restructure (nothing of size [B,V,128] materializes):
//   G[b,a,f] = sum_v ew*data, E[b,a] = sum_v ew
//   agg[a,p] = (sum_f Wflr[f,p]*G[a,f] + bflr[p]*E[a]) / V
//   M[a,n]   = sum_p agg[a,p]*Wout[a*P+p,n]
//   out[v,n] = mask * (sum_a ew[v,a]*M[a,n] + bout[n])

#define B_ 64
#define V_ 4096
#define F_ 16
#define A_ 8
#define P_ 16
#define NF_ 16
#define SPLIT1 4              // kernel A: 4 blocks/batch -> 256 blocks
#define SPLIT2 8              // kernel B: 8 blocks/batch -> 512 blocks
#define GE_ (A_*F_ + A_)      // 136 partials per kernel-A block

typedef unsigned int uint32;
typedef unsigned short u16;

__device__ __forceinline__ float bflo(uint32 u){ union{uint32 i;float f;}x; x.i=u<<16; return x.f; }
__device__ __forceinline__ float bfhi(uint32 u){ union{uint32 i;float f;}x; x.i=u&0xffff0000u; return x.f; }

// dtype probe: bf16-packed words carry the low element's exponent in bits 14..7
// (always ~[100,135] for N(0,1)); f32 words have uniform mantissa bits there
// (p~0.14). Vote 11/16. R2 evidence: chose f32 on this harness.
__device__ __forceinline__ bool detect_bf16(const void* data){
  const uint32* w = (const uint32*)data;
  int c = 0;
  #pragma unroll
  for (int i=0;i<16;++i){
    uint32 e = (w[i]>>7) & 0xffu;
    c += (e>=100u && e<=135u) ? 1 : 0;
  }
  return c >= 11;
}

template<bool BF16>
__device__ __forceinline__ float ldw(const void* p, int i){
  return BF16 ? bflo((uint32)((const u16*)p)[i]) : ((const float*)p)[i];
}

template<bool BF16>
__device__ __forceinline__ void load_vertex(const void* base, size_t v, float* d){
  if (BF16){
    const uint4* p = (const uint4*)((const u16*)base + v*F_);
    uint4 r0=p[0], r1=p[1];
    d[0]=bflo(r0.x); d[1]=bfhi(r0.x); d[2]=bflo(r0.y); d[3]=bfhi(r0.y);
    d[4]=bflo(r0.z); d[5]=bfhi(r0.z); d[6]=bflo(r0.w); d[7]=bfhi(r0.w);
    d[8]=bflo(r1.x); d[9]=bfhi(r1.x); d[10]=bflo(r1.y); d[11]=bfhi(r1.y);
    d[12]=bflo(r1.z); d[13]=bfhi(r1.z); d[14]=bflo(r1.w); d[15]=bfhi(r1.w);
  } else {
    const float4* p = (const float4*)((const float*)base + v*F_);
    float4 a=p[0], b=p[1], c=p[2], e=p[3];
    d[0]=a.x; d[1]=a.y; d[2]=a.z; d[3]=a.w;
    d[4]=b.x; d[5]=b.y; d[6]=b.z; d[7]=b.w;
    d[8]=c.x; d[9]=c.y; d[10]=c.z; d[11]=c.w;
    d[12]=e.x; d[13]=e.y; d[14]=e.z; d[15]=e.w;
  }
}

// ---------------- Kernel A: G[a,f], E[a] per (batch, split) ----------------
template<bool BF16>
__device__ __forceinline__ void agg_body(
    const void* __restrict__ data, const int* __restrict__ nv,
    const void* __restrict__ Ws, const void* __restrict__ bs,
    float* __restrict__ partial)
{
  __shared__ __align__(16) float sWs[F_*A_];
  __shared__ float sbs[A_];
  __shared__ float sred[4][GE_];

  const int tid = threadIdx.x;
  if (tid < F_*A_) sWs[tid] = ldw<BF16>(Ws, tid);
  if (tid < A_)    sbs[tid] = ldw<BF16>(bs, tid);
  const int b = blockIdx.x >> 2;
  const int s = blockIdx.x & 3;
  const int nvb = nv[b];
  __syncthreads();

  float G[A_*F_], E[A_];
  #pragma unroll
  for (int i=0;i<A_*F_;++i) G[i]=0.f;
  #pragma unroll
  for (int i=0;i<A_;++i) E[i]=0.f;

  const int vbase = s*(V_/SPLIT1);              // 1024 vertices per block
  const size_t voff = (size_t)b*V_ + vbase;

  #pragma unroll
  for (int it=0; it<2; ++it) {                  // 2 x (2 vertices/thread)
    const int vl0 = it*512 + tid;
    const int vl1 = vl0 + 256;
    float d0[16], d1[16];
    load_vertex<BF16>(data, voff+vl0, d0);
    load_vertex<BF16>(data, voff+vl1, d1);
    const float m0 = (vbase+vl0 < nvb) ? 1.f : 0.f;
    const float m1 = (vbase+vl1 < nvb) ? 1.f : 0.f;

    float t0[A_], t1[A_];
    #pragma unroll
    for (int a=0;a<A_;++a){ t0[a]=sbs[a]; t1[a]=sbs[a]; }
    #pragma unroll
    for (int f=0; f<F_; ++f){
      const float4 w0 = *(const float4*)&sWs[f*A_];
      const float4 w1 = *(const float4*)&sWs[f*A_+4];
      const float wa[8] = {w0.x,w0.y,w0.z,w0.w,w1.x,w1.y,w1.z,w1.w};
      #pragma unroll
      for (int a=0;a<A_;++a){
        t0[a] = fmaf(d0[f], wa[a], t0[a]);
        t1[a] = fmaf(d1[f], wa[a], t1[a]);
      }
    }
    #pragma unroll
    for (int a=0;a<A_;++a){
      const float e0 = m0*__expf(-t0[a]*t0[a]);
      const float e1 = m1*__expf(-t1[a]*t1[a]);
      E[a] += e0+e1;
      #pragma unroll
      for (int f=0;f<F_;++f)
        G[a*F_+f] = fmaf(e0, d0[f], fmaf(e1, d1[f], G[a*F_+f]));
    }
  }

  const int lane = tid & 63, wv = tid >> 6;
  #pragma unroll
  for (int i=0;i<A_*F_;++i){
    float x = G[i];
    x += __shfl_xor(x,1);  x += __shfl_xor(x,2);  x += __shfl_xor(x,4);
    x += __shfl_xor(x,8);  x += __shfl_xor(x,16); x += __shfl_xor(x,32);
    if (lane==0) sred[wv][i]=x;
  }
  #pragma unroll
  for (int i=0;i<A_;++i){
    float x = E[i];
    x += __shfl_xor(x,1);  x += __shfl_xor(x,2);  x += __shfl_xor(x,4);
    x += __shfl_xor(x,8);  x += __shfl_xor(x,16); x += __shfl_xor(x,32);
    if (lane==0) sred[wv][A_*F_+i]=x;
  }
  __syncthreads();
  if (tid < GE_){
    partial[(size_t)blockIdx.x*GE_ + tid] =
        sred[0][tid]+sred[1][tid]+sred[2][tid]+sred[3][tid];
  }
}

__global__ __launch_bounds__(256, 1) void k_agg(
    const void* __restrict__ data, const int* __restrict__ nv,
    const void* __restrict__ Ws, const void* __restrict__ bs,
    float* __restrict__ partial)
{
  if (detect_bf16(data)) agg_body<true >(data, nv, Ws, bs, partial);
  else                   agg_body<false>(data, nv, Ws, bs, partial);
}

// ------------- Kernel B: agg->M per batch, recompute ew, emit f32 out -------------
template<bool BF16>
__device__ __forceinline__ void out_body(
    const void* __restrict__ data, const int* __restrict__ nv,
    const void* __restrict__ Wflr, const void* __restrict__ bflr,
    const void* __restrict__ Ws, const void* __restrict__ bs,
    const void* __restrict__ Wout, const void* __restrict__ bout,
    const float* __restrict__ partial, float* __restrict__ out)
{
  __shared__ __align__(16) float sWs[F_*A_];
  __shared__ __align__(16) float sWf[F_*P_];
  __shared__ float sbf[P_], sbs[A_], sbo[NF_];
  __shared__ float sGE[GE_];
  __shared__ float sagg[A_*P_];
  __shared__ __align__(16) float sM[A_*NF_];

  const int tid = threadIdx.x;
  const int b = blockIdx.x >> 3;
  const int s = blockIdx.x & 7;

  if (tid < F_*P_) sWf[tid] = ldw<BF16>(Wflr, tid);
  if (tid < F_*A_) sWs[tid] = ldw<BF16>(Ws, tid);
  if (tid < P_)    sbf[tid] = ldw<BF16>(bflr, tid);
  if (tid < A_)    sbs[tid] = ldw<BF16>(bs, tid);
  if (tid < NF_)   sbo[tid] = ldw<BF16>(bout, tid);
  if (tid < GE_) {
    const float* pp = partial + (size_t)(b*SPLIT1)*GE_ + tid;
    sGE[tid] = pp[0] + pp[GE_] + pp[2*GE_] + pp[3*GE_];
  }
  const int nvb = nv[b];
  __syncthreads();

  if (tid < A_*P_) {                       // agg[a,p]
    const int a = tid >> 4, p = tid & 15;
    float acc = sGE[A_*F_ + a] * sbf[p];
    #pragma unroll
    for (int f=0;f<F_;++f) acc = fmaf(sGE[a*F_+f], sWf[f*P_+p], acc);
    sagg[tid] = acc * (1.0f/(float)V_);
  }
  __syncthreads();
  if (tid < A_*NF_) {                      // M[a,n]
    const int a = tid >> 4, n = tid & 15;
    float m = 0.f;
    #pragma unroll
    for (int p=0;p<P_;++p)
      m = fmaf(sagg[a*P_+p], ldw<BF16>(Wout, (a*P_+p)*NF_+n), m);
    sM[tid] = m;
  }
  __syncthreads();

  const int vbase = s*(V_/SPLIT2);         // 512 vertices per block
  const size_t voff = (size_t)b*V_ + vbase;
  float* obase = out + ((size_t)b*V_ + vbase)*NF_;

  const int vl0 = tid, vl1 = tid + 256;
  float d0[16], d1[16];
  load_vertex<BF16>(data, voff+vl0, d0);
  load_vertex<BF16>(data, voff+vl1, d1);
  const float m0 = (vbase+vl0 < nvb) ? 1.f : 0.f;
  const float m1 = (vbase+vl1 < nvb) ? 1.f : 0.f;

  float t0[A_], t1[A_];
  #pragma unroll
  for (int a=0;a<A_;++a){ t0[a]=sbs[a]; t1[a]=sbs[a]; }
  #pragma unroll
  for (int f=0; f<F_; ++f){
    const float4 w0 = *(const float4*)&sWs[f*A_];
    const float4 w1 = *(const float4*)&sWs[f*A_+4];
    const float wa[8] = {w0.x,w0.y,w0.z,w0.w,w1.x,w1.y,w1.z,w1.w};
    #pragma unroll
    for (int a=0;a<A_;++a){
      t0[a] = fmaf(d0[f], wa[a], t0[a]);
      t1[a] = fmaf(d1[f], wa[a], t1[a]);
    }
  }
  float e0[A_], e1[A_];
  #pragma unroll
  for (int a=0;a<A_;++a){
    e0[a] = m0*__expf(-t0[a]*t0[a]);
    e1[a] = m1*__expf(-t1[a]*t1[a]);
  }

  float o0[NF_], o1[NF_];
  #pragma unroll
  for (int n=0;n<NF_;++n){ o0[n]=sbo[n]; o1[n]=sbo[n]; }
  #pragma unroll
  for (int a=0;a<A_;++a){
    const float4 q0 = *(const float4*)&sM[a*NF_];
    const float4 q1 = *(const float4*)&sM[a*NF_+4];
    const float4 q2 = *(const float4*)&sM[a*NF_+8];
    const float4 q3 = *(const float4*)&sM[a*NF_+12];
    const float ma[16] = {q0.x,q0.y,q0.z,q0.w, q1.x,q1.y,q1.z,q1.w,
                          q2.x,q2.y,q2.z,q2.w, q3.x,q3.y,q3.z,q3.w};
    #pragma unroll
    for (int n=0;n<NF_;++n){
      o0[n] = fmaf(e0[a], ma[n], o0[n]);
      o1[n] = fmaf(e1[a], ma[n], o1[n]);
    }
  }

  float4* ob0 = (float4*)(obase + (size_t)vl0*NF_);
  float4* ob1 = (float4*)(obase + (size_t)vl1*NF_);
  ob0[0] = make_float4(o0[0]*m0,  o0[1]*m0,  o0[2]*m0,  o0[3]*m0);
  ob0[1] = make_float4(o0[4]*m0,  o0[5]*m0,  o0[6]*m0,  o0[7]*m0);
  ob0[2] = make_float4(o0[8]*m0,  o0[9]*m0,  o0[10]*m0, o0[11]*m0);
  ob0[3] = make_float4(o0[12]*m0, o0[13]*m0, o0[14]*m0, o0[15]*m0);
  ob1[0] = make_float4(o1[0]*m1,  o1[1]*m1,  o1[2]*m1,  o1[3]*m1);
  ob1[1] = make_float4(o1[4]*m1,  o1[5]*m1,  o1[6]*m1,  o1[7]*m1);
  ob1[2] = make_float4(o1[8]*m1,  o1[9]*m1,  o1[10]*m1, o1[11]*m1);
  ob1[3] = make_float4(o1[12]*m1, o1[13]*m1, o1[14]*m1, o1[15]*m1);
}

__global__ __launch_bounds__(256, 2) void k_out(
    const void* __restrict__ data, const int* __restrict__ nv,
    const void* __restrict__ Wflr, const void* __restrict__ bflr,
    const void* __restrict__ Ws, const void* __restrict__ bs,
    const void* __restrict__ Wout, const void* __restrict__ bout,
    const float* __restrict__ partial, float* __restrict__ out)
{
  if (detect_bf16(data))
    out_body<true >(data, nv, Wflr, bflr, Ws, bs, Wout, bout, partial, out);
  else
    out_body<false>(data, nv, Wflr, bflr, Ws, bs, Wout, bout, partial, out);
}

extern "C" void kernel_launch(void* const* d_in, const int* in_sizes, int n_in,
                              void* d_out, int out_size, void* d_ws, size_t ws_size,
                              hipStream_t stream) {
  const void* data = d_in[0];
  const int*  nv   = (const int*)d_in[1];
  const void* Wflr = d_in[2];
  const void* bflr = d_in[3];
  const void* Ws   = d_in[4];
  const void* bs   = d_in[5];
  const void* Wout = d_in[6];
  const void* bout = d_in[7];
  float* out = (float*)d_out;
  float* partial = (float*)d_ws;   // 256*136*4 = 139264 B, fully overwritten by k_agg

  hipLaunchKernelGGL(k_agg, dim3(B_*SPLIT1), dim3(256), 0, stream,
                     data, nv, Ws, bs, partial);
  hipLaunchKernelGGL(k_out, dim3(B_*SPLIT2), dim3(256), 0, stream,
                     data, nv, Wflr, bflr, Ws, bs, Wout, bout, partial, out);
}

// Round 4
// 121.333 us; speedup vs baseline: 1.0084x; 1.0084x over previous
//
#include <hip/hip_runtime.h>

// GarNet: B=64 V=4096 F=16 A=8 P=16 NF=16. Inputs f32 (R2-confirmed), output f32.
// SINGLE fused kernel: grid 256 = 1 block/CU (all blocks co-resident even at max
// VGPR -> per-batch spin barrier is deadlock-free; bounded spin as a safety net).
// Each block: 1024 vertices, phase 1 accumulates G[a,f],E[a]; agent-scope atomics
// publish partials + MAGIC flag; 4 sibling blocks/batch fan-in; phase 2 reuses
// register-held e[v,a] (no data re-read, no dist recompute) to emit out.
//
//   G[b,a,f]=sum_v ew*d, E=sum_v ew ; agg=(Wflr^T G + bflr E)/V ; M=agg*Wout
//   out[v,n]=mask*(sum_a ew[v,a]*M[a,n]+bout[n])

#define B_ 64
#define V_ 4096
#define F_ 16
#define A_ 8
#define P_ 16
#define NF_ 16
#define SPB 4                 // blocks per batch
#define NBLK (B_*SPB)         // 256 blocks = 1 per CU
#define VPB (V_/SPB)          // 1024 vertices per block
#define GE_ (A_*F_ + A_)      // 136 partials per block
#define MAGIC 0x5CA1AB1Eu

typedef unsigned int uint32;
typedef unsigned short u16;

__device__ __forceinline__ float bflo(uint32 u){ union{uint32 i;float f;}x; x.i=u<<16; return x.f; }
__device__ __forceinline__ float bfhi(uint32 u){ union{uint32 i;float f;}x; x.i=u&0xffff0000u; return x.f; }

// dtype probe (R2: votes f32 on this harness; kept as zero-cost insurance)
__device__ __forceinline__ bool detect_bf16(const void* data){
  const uint32* w = (const uint32*)data;
  int c = 0;
  #pragma unroll
  for (int i=0;i<16;++i){
    uint32 e = (w[i]>>7) & 0xffu;
    c += (e>=100u && e<=135u) ? 1 : 0;
  }
  return c >= 11;
}

template<bool BF16>
__device__ __forceinline__ float ldw(const void* p, int i){
  return BF16 ? bflo((uint32)((const u16*)p)[i]) : ((const float*)p)[i];
}

template<bool BF16>
__device__ __forceinline__ void load_vertex(const void* base, size_t v, float* d){
  if (BF16){
    const uint4* p = (const uint4*)((const u16*)base + v*F_);
    uint4 r0=p[0], r1=p[1];
    d[0]=bflo(r0.x); d[1]=bfhi(r0.x); d[2]=bflo(r0.y); d[3]=bfhi(r0.y);
    d[4]=bflo(r0.z); d[5]=bfhi(r0.z); d[6]=bflo(r0.w); d[7]=bfhi(r0.w);
    d[8]=bflo(r1.x); d[9]=bfhi(r1.x); d[10]=bflo(r1.y); d[11]=bfhi(r1.y);
    d[12]=bflo(r1.z); d[13]=bfhi(r1.z); d[14]=bflo(r1.w); d[15]=bfhi(r1.w);
  } else {
    const float4* p = (const float4*)((const float*)base + v*F_);
    float4 a=p[0], b=p[1], c=p[2], e=p[3];
    d[0]=a.x; d[1]=a.y; d[2]=a.z; d[3]=a.w;
    d[4]=b.x; d[5]=b.y; d[6]=b.z; d[7]=b.w;
    d[8]=c.x; d[9]=c.y; d[10]=c.z; d[11]=c.w;
    d[12]=e.x; d[13]=e.y; d[14]=e.z; d[15]=e.w;
  }
}

template<bool BF16>
__device__ __forceinline__ void fused_body(
    const void* __restrict__ data, const int* __restrict__ nv,
    const void* __restrict__ Wflr, const void* __restrict__ bflr,
    const void* __restrict__ Ws, const void* __restrict__ bs,
    const void* __restrict__ Wout, const void* __restrict__ bout,
    float* __restrict__ partials, uint32* __restrict__ flags,
    float* __restrict__ out)
{
  __shared__ __align__(16) float sWs[F_*A_];
  __shared__ __align__(16) float sWf[F_*P_];
  __shared__ float sbs[A_], sbf[P_], sbo[NF_];
  __shared__ float sred[4][GE_];
  __shared__ float sGE[GE_];
  __shared__ float sagg[A_*P_];
  __shared__ __align__(16) float sM[A_*NF_];

  const int tid = threadIdx.x;
  const int bid = blockIdx.x;
  const int b = bid >> 2;
  const int s = bid & 3;

  if (tid < F_*A_) sWs[tid] = ldw<BF16>(Ws, tid);
  if (tid < F_*P_) sWf[tid] = ldw<BF16>(Wflr, tid);
  if (tid < A_)    sbs[tid] = ldw<BF16>(bs, tid);
  if (tid < P_)    sbf[tid] = ldw<BF16>(bflr, tid);
  if (tid < NF_)   sbo[tid] = ldw<BF16>(bout, tid);
  const int nvb = nv[b];
  __syncthreads();

  const int vbase = s*VPB;
  const size_t voff = (size_t)b*V_ + vbase;

  float G[A_*F_], E[A_];
  float e_all[4][A_];                     // ew per held vertex, survives barrier
  #pragma unroll
  for (int i=0;i<A_*F_;++i) G[i]=0.f;
  #pragma unroll
  for (int i=0;i<A_;++i) E[i]=0.f;

  #pragma unroll
  for (int half=0; half<2; ++half) {      // 2 x (2 vertices/thread)
    const int j0 = 2*half, j1 = 2*half+1;
    const int vl0 = j0*256 + tid;
    const int vl1 = j1*256 + tid;
    float d0[16], d1[16];
    load_vertex<BF16>(data, voff+vl0, d0);
    load_vertex<BF16>(data, voff+vl1, d1);
    const float m0 = (vbase+vl0 < nvb) ? 1.f : 0.f;
    const float m1 = (vbase+vl1 < nvb) ? 1.f : 0.f;

    float t0[A_], t1[A_];
    #pragma unroll
    for (int a=0;a<A_;++a){ t0[a]=sbs[a]; t1[a]=sbs[a]; }
    #pragma unroll
    for (int f=0; f<F_; ++f){
      const float4 w0 = *(const float4*)&sWs[f*A_];
      const float4 w1 = *(const float4*)&sWs[f*A_+4];
      const float wa[8] = {w0.x,w0.y,w0.z,w0.w,w1.x,w1.y,w1.z,w1.w};
      #pragma unroll
      for (int a=0;a<A_;++a){
        t0[a] = fmaf(d0[f], wa[a], t0[a]);
        t1[a] = fmaf(d1[f], wa[a], t1[a]);
      }
    }
    #pragma unroll
    for (int a=0;a<A_;++a){
      const float e0 = m0*__expf(-t0[a]*t0[a]);
      const float e1 = m1*__expf(-t1[a]*t1[a]);
      e_all[j0][a] = e0;
      e_all[j1][a] = e1;
      E[a] += e0+e1;
      #pragma unroll
      for (int f=0;f<F_;++f)
        G[a*F_+f] = fmaf(e0, d0[f], fmaf(e1, d1[f], G[a*F_+f]));
    }
  }

  // intra-block reduce: 64-lane butterfly, then 4 waves via LDS
  const int lane = tid & 63, wv = tid >> 6;
  #pragma unroll
  for (int i=0;i<A_*F_;++i){
    float x = G[i];
    x += __shfl_xor(x,1);  x += __shfl_xor(x,2);  x += __shfl_xor(x,4);
    x += __shfl_xor(x,8);  x += __shfl_xor(x,16); x += __shfl_xor(x,32);
    if (lane==0) sred[wv][i]=x;
  }
  #pragma unroll
  for (int i=0;i<A_;++i){
    float x = E[i];
    x += __shfl_xor(x,1);  x += __shfl_xor(x,2);  x += __shfl_xor(x,4);
    x += __shfl_xor(x,8);  x += __shfl_xor(x,16); x += __shfl_xor(x,32);
    if (lane==0) sred[wv][A_*F_+i]=x;
  }
  __syncthreads();

  // publish partials (agent scope -> coherent past per-XCD L2)
  if (tid < GE_){
    const float ps = sred[0][tid]+sred[1][tid]+sred[2][tid]+sred[3][tid];
    __hip_atomic_store(&partials[(size_t)bid*GE_ + tid], ps,
                       __ATOMIC_RELAXED, __HIP_MEMORY_SCOPE_AGENT);
  }
  __syncthreads();                        // compiler drains vmcnt before barrier
  if (tid == 0)
    __hip_atomic_store(&flags[bid], MAGIC,
                       __ATOMIC_RELEASE, __HIP_MEMORY_SCOPE_AGENT);

  // fan-in: wait for 4 sibling blocks of this batch. All 256 blocks are
  // co-resident (grid==CU count, 1 block always fits) -> no deadlock; bounded
  // spin converts any pathological case into a wrong answer, never a hang.
  if (tid < SPB) {
    const uint32* fp = &flags[b*SPB + tid];
    int it = 0;
    while (__hip_atomic_load(fp, __ATOMIC_ACQUIRE, __HIP_MEMORY_SCOPE_AGENT) != MAGIC) {
      if (++it > 200000) break;           // ~tens of ms >> expected ~µs skew
      __builtin_amdgcn_s_sleep(8);
    }
  }
  __syncthreads();

  // reduce 4 partial sets -> G/E for the whole batch
  if (tid < GE_){
    float v = 0.f;
    #pragma unroll
    for (int k=0;k<SPB;++k)
      v += __hip_atomic_load(&partials[(size_t)(b*SPB+k)*GE_ + tid],
                             __ATOMIC_RELAXED, __HIP_MEMORY_SCOPE_AGENT);
    sGE[tid] = v;
  }
  __syncthreads();

  if (tid < A_*P_) {                      // agg[a,p]
    const int a = tid >> 4, p = tid & 15;
    float acc = sGE[A_*F_ + a] * sbf[p];
    #pragma unroll
    for (int f=0;f<F_;++f) acc = fmaf(sGE[a*F_+f], sWf[f*P_+p], acc);
    sagg[tid] = acc * (1.0f/(float)V_);
  }
  __syncthreads();
  if (tid < A_*NF_) {                     // M[a,n]
    const int a = tid >> 4, n = tid & 15;
    float m = 0.f;
    #pragma unroll
    for (int p=0;p<P_;++p)
      m = fmaf(sagg[a*P_+p], ldw<BF16>(Wout, (a*P_+p)*NF_+n), m);
    sM[tid] = m;
  }
  __syncthreads();

  // phase 2: register-held e -> out, no data re-read
  #pragma unroll
  for (int j=0;j<4;++j){
    const int vl = j*256 + tid;
    const float m = (vbase+vl < nvb) ? 1.f : 0.f;
    float o[NF_];
    #pragma unroll
    for (int n=0;n<NF_;++n) o[n]=sbo[n];
    #pragma unroll
    for (int a=0;a<A_;++a){
      const float e = e_all[j][a];
      const float4 q0 = *(const float4*)&sM[a*NF_];
      const float4 q1 = *(const float4*)&sM[a*NF_+4];
      const float4 q2 = *(const float4*)&sM[a*NF_+8];
      const float4 q3 = *(const float4*)&sM[a*NF_+12];
      const float ma[16] = {q0.x,q0.y,q0.z,q0.w, q1.x,q1.y,q1.z,q1.w,
                            q2.x,q2.y,q2.z,q2.w, q3.x,q3.y,q3.z,q3.w};
      #pragma unroll
      for (int n=0;n<NF_;++n) o[n] = fmaf(e, ma[n], o[n]);
    }
    float4* ob = (float4*)(out + (voff+vl)*NF_);
    ob[0] = make_float4(o[0]*m,  o[1]*m,  o[2]*m,  o[3]*m);
    ob[1] = make_float4(o[4]*m,  o[5]*m,  o[6]*m,  o[7]*m);
    ob[2] = make_float4(o[8]*m,  o[9]*m,  o[10]*m, o[11]*m);
    ob[3] = make_float4(o[12]*m, o[13]*m, o[14]*m, o[15]*m);
  }
}

__global__ __launch_bounds__(256, 1) void k_fused(
    const void* __restrict__ data, const int* __restrict__ nv,
    const void* __restrict__ Wflr, const void* __restrict__ bflr,
    const void* __restrict__ Ws, const void* __restrict__ bs,
    const void* __restrict__ Wout, const void* __restrict__ bout,
    float* __restrict__ partials, uint32* __restrict__ flags,
    float* __restrict__ out)
{
  if (detect_bf16(data))
    fused_body<true >(data, nv, Wflr, bflr, Ws, bs, Wout, bout, partials, flags, out);
  else
    fused_body<false>(data, nv, Wflr, bflr, Ws, bs, Wout, bout, partials, flags, out);
}

extern "C" void kernel_launch(void* const* d_in, const int* in_sizes, int n_in,
                              void* d_out, int out_size, void* d_ws, size_t ws_size,
                              hipStream_t stream) {
  const void* data = d_in[0];
  const int*  nv   = (const int*)d_in[1];
  const void* Wflr = d_in[2];
  const void* bflr = d_in[3];
  const void* Ws   = d_in[4];
  const void* bs   = d_in[5];
  const void* Wout = d_in[6];
  const void* bout = d_in[7];
  float* out = (float*)d_out;
  float*  partials = (float*)d_ws;                       // 256*136 f32
  uint32* flags    = (uint32*)((char*)d_ws + (size_t)NBLK*GE_*sizeof(float));
  // flags poisoned to 0xAAAAAAAA != MAGIC each launch; pattern is also
  // idempotent across replays without re-poison (same inputs -> same partials).

  hipLaunchKernelGGL(k_fused, dim3(NBLK), dim3(256), 0, stream,
                     data, nv, Wflr, bflr, Ws, bs, Wout, bout,
                     partials, flags, out);
}

// Round 5
// 99.490 us; speedup vs baseline: 1.2298x; 1.2195x over previous
//
#include <hip/hip_runtime.h>

// GarNet: B=64 V=4096 F=16 A=8 P=16 NF=16. Inputs f32 (R2-confirmed), output f32.
// R4 lesson: 816-op shuffle butterfly under G[128] register pressure = ~45 us of
// exposed ds-latency at 1 wave/SIMD. This round: zero-shuffle LDS tree reduction,
// two kernels (no grid barrier -> no 1-block/CU pin), 2 blocks/CU for k_agg,
// 4 blocks/CU for k_out.
//
//   G[b,a,f]=sum_v ew*d, E=sum_v ew ; agg=(Wflr^T G + bflr E)/V ; M=agg*Wout
//   out[v,n]=mask*(sum_a ew[v,a]*M[a,n]+bout[n])

#define B_ 64
#define V_ 4096
#define F_ 16
#define A_ 8
#define P_ 16
#define NF_ 16
#define SPLIT1 8              // k_agg: 8 blocks/batch -> 512 blocks (2/CU)
#define SPLIT2 16             // k_out: 16 blocks/batch -> 1024 blocks (4/CU)
#define GE_ (A_*F_ + A_)      // 136 partials per k_agg block (= 4 chunks of 34)
#define CH_ 34                // chunk size for LDS tree reduction

typedef unsigned int uint32;
typedef unsigned short u16;

__device__ __forceinline__ float bflo(uint32 u){ union{uint32 i;float f;}x; x.i=u<<16; return x.f; }
__device__ __forceinline__ float bfhi(uint32 u){ union{uint32 i;float f;}x; x.i=u&0xffff0000u; return x.f; }

// dtype probe (R2: votes f32 on this harness; kept as cheap insurance)
__device__ __forceinline__ bool detect_bf16(const void* data){
  const uint32* w = (const uint32*)data;
  int c = 0;
  #pragma unroll
  for (int i=0;i<16;++i){
    uint32 e = (w[i]>>7) & 0xffu;
    c += (e>=100u && e<=135u) ? 1 : 0;
  }
  return c >= 11;
}

template<bool BF16>
__device__ __forceinline__ float ldw(const void* p, int i){
  return BF16 ? bflo((uint32)((const u16*)p)[i]) : ((const float*)p)[i];
}

template<bool BF16>
__device__ __forceinline__ void load_vertex(const void* base, size_t v, float* d){
  if (BF16){
    const uint4* p = (const uint4*)((const u16*)base + v*F_);
    uint4 r0=p[0], r1=p[1];
    d[0]=bflo(r0.x); d[1]=bfhi(r0.x); d[2]=bflo(r0.y); d[3]=bfhi(r0.y);
    d[4]=bflo(r0.z); d[5]=bfhi(r0.z); d[6]=bflo(r0.w); d[7]=bfhi(r0.w);
    d[8]=bflo(r1.x); d[9]=bfhi(r1.x); d[10]=bflo(r1.y); d[11]=bfhi(r1.y);
    d[12]=bflo(r1.z); d[13]=bfhi(r1.z); d[14]=bflo(r1.w); d[15]=bfhi(r1.w);
  } else {
    const float4* p = (const float4*)((const float*)base + v*F_);
    float4 a=p[0], b=p[1], c=p[2], e=p[3];
    d[0]=a.x; d[1]=a.y; d[2]=a.z; d[3]=a.w;
    d[4]=b.x; d[5]=b.y; d[6]=b.z; d[7]=b.w;
    d[8]=c.x; d[9]=c.y; d[10]=c.z; d[11]=c.w;
    d[12]=e.x; d[13]=e.y; d[14]=e.z; d[15]=e.w;
  }
}

// ---------------- Kernel A: G[a,f], E[a] per (batch, split) ----------------
template<bool BF16>
__device__ __forceinline__ void agg_body(
    const void* __restrict__ data, const int* __restrict__ nv,
    const void* __restrict__ Ws, const void* __restrict__ bs,
    float* __restrict__ partial)
{
  __shared__ __align__(16) float sWs[F_*A_];
  __shared__ float sbs[A_];
  __shared__ float red[256][CH_+1];      // +1 pad: write stride 35 (=3 mod 32)
  __shared__ float red2[4][CH_];

  const int tid = threadIdx.x;
  if (tid < F_*A_) sWs[tid] = ldw<BF16>(Ws, tid);
  if (tid < A_)    sbs[tid] = ldw<BF16>(bs, tid);
  const int b = blockIdx.x >> 3;
  const int s = blockIdx.x & 7;
  const int nvb = nv[b];
  __syncthreads();

  float G[A_*F_], E[A_];
  #pragma unroll
  for (int i=0;i<A_*F_;++i) G[i]=0.f;
  #pragma unroll
  for (int i=0;i<A_;++i) E[i]=0.f;

  const int vbase = s*(V_/SPLIT1);       // 512 vertices per block
  const size_t voff = (size_t)b*V_ + vbase;

  // 2 vertices per thread, both loads issued up front
  const int vl0 = tid, vl1 = tid + 256;
  float d0[16], d1[16];
  load_vertex<BF16>(data, voff+vl0, d0);
  load_vertex<BF16>(data, voff+vl1, d1);
  const float m0 = (vbase+vl0 < nvb) ? 1.f : 0.f;
  const float m1 = (vbase+vl1 < nvb) ? 1.f : 0.f;

  float t0[A_], t1[A_];
  #pragma unroll
  for (int a=0;a<A_;++a){ t0[a]=sbs[a]; t1[a]=sbs[a]; }
  #pragma unroll
  for (int f=0; f<F_; ++f){
    const float4 w0 = *(const float4*)&sWs[f*A_];
    const float4 w1 = *(const float4*)&sWs[f*A_+4];
    const float wa[8] = {w0.x,w0.y,w0.z,w0.w,w1.x,w1.y,w1.z,w1.w};
    #pragma unroll
    for (int a=0;a<A_;++a){
      t0[a] = fmaf(d0[f], wa[a], t0[a]);
      t1[a] = fmaf(d1[f], wa[a], t1[a]);
    }
  }
  #pragma unroll
  for (int a=0;a<A_;++a){
    const float e0 = m0*__expf(-t0[a]*t0[a]);
    const float e1 = m1*__expf(-t1[a]*t1[a]);
    E[a] = e0+e1;
    #pragma unroll
    for (int f=0;f<F_;++f)
      G[a*F_+f] = fmaf(e0, d0[f], e1*d1[f]);
  }

  // zero-shuffle LDS tree reduction, 4 chunks of 34 values
  #pragma unroll
  for (int c=0;c<4;++c){
    #pragma unroll
    for (int j=0;j<CH_;++j){
      const int idx = c*CH_ + j;
      red[tid][j] = (idx < A_*F_) ? G[idx] : E[idx - A_*F_];
    }
    __syncthreads();
    if (tid < 4*CH_){                    // 136 threads: sum 64 rows each
      const int j = tid >> 2, q = tid & 3;
      float acc = 0.f;
      #pragma unroll 8
      for (int i=0;i<64;++i) acc += red[64*q + i][j];
      red2[q][j] = acc;
    }
    __syncthreads();
    if (tid < CH_)
      partial[(size_t)blockIdx.x*GE_ + c*CH_ + tid] =
          red2[0][tid]+red2[1][tid]+red2[2][tid]+red2[3][tid];
    __syncthreads();                     // red reused next chunk
  }
}

__global__ __launch_bounds__(256, 2) void k_agg(
    const void* __restrict__ data, const int* __restrict__ nv,
    const void* __restrict__ Ws, const void* __restrict__ bs,
    float* __restrict__ partial)
{
  if (detect_bf16(data)) agg_body<true >(data, nv, Ws, bs, partial);
  else                   agg_body<false>(data, nv, Ws, bs, partial);
}

// ------------- Kernel B: agg->M per batch, recompute ew, emit f32 out -------------
template<bool BF16>
__device__ __forceinline__ void out_body(
    const void* __restrict__ data, const int* __restrict__ nv,
    const void* __restrict__ Wflr, const void* __restrict__ bflr,
    const void* __restrict__ Ws, const void* __restrict__ bs,
    const void* __restrict__ Wout, const void* __restrict__ bout,
    const float* __restrict__ partial, float* __restrict__ out)
{
  __shared__ __align__(16) float sWs[F_*A_];
  __shared__ __align__(16) float sWf[F_*P_];
  __shared__ float sbf[P_], sbs[A_], sbo[NF_];
  __shared__ float sGE[GE_];
  __shared__ float sagg[A_*P_];
  __shared__ __align__(16) float sM[A_*NF_];

  const int tid = threadIdx.x;
  const int b = blockIdx.x >> 4;
  const int s = blockIdx.x & 15;

  if (tid < F_*P_) sWf[tid] = ldw<BF16>(Wflr, tid);
  if (tid < F_*A_) sWs[tid] = ldw<BF16>(Ws, tid);
  if (tid < P_)    sbf[tid] = ldw<BF16>(bflr, tid);
  if (tid < A_)    sbs[tid] = ldw<BF16>(bs, tid);
  if (tid < NF_)   sbo[tid] = ldw<BF16>(bout, tid);
  if (tid < GE_) {
    const float* pp = partial + (size_t)(b*SPLIT1)*GE_ + tid;
    float v = 0.f;
    #pragma unroll
    for (int k=0;k<SPLIT1;++k) v += pp[(size_t)k*GE_];
    sGE[tid] = v;
  }
  const int nvb = nv[b];
  __syncthreads();

  if (tid < A_*P_) {                     // agg[a,p]
    const int a = tid >> 4, p = tid & 15;
    float acc = sGE[A_*F_ + a] * sbf[p];
    #pragma unroll
    for (int f=0;f<F_;++f) acc = fmaf(sGE[a*F_+f], sWf[f*P_+p], acc);
    sagg[tid] = acc * (1.0f/(float)V_);
  }
  __syncthreads();
  if (tid < A_*NF_) {                    // M[a,n]
    const int a = tid >> 4, n = tid & 15;
    float m = 0.f;
    #pragma unroll
    for (int p=0;p<P_;++p)
      m = fmaf(sagg[a*P_+p], ldw<BF16>(Wout, (a*P_+p)*NF_+n), m);
    sM[tid] = m;
  }
  __syncthreads();

  // 1 vertex per thread
  const int vbase = s*(V_/SPLIT2);       // 256 vertices per block
  const int vl = tid;
  const size_t voff = (size_t)b*V_ + vbase;
  float d0[16];
  load_vertex<BF16>(data, voff+vl, d0);
  const float m = (vbase+vl < nvb) ? 1.f : 0.f;

  float t0[A_];
  #pragma unroll
  for (int a=0;a<A_;++a) t0[a]=sbs[a];
  #pragma unroll
  for (int f=0; f<F_; ++f){
    const float4 w0 = *(const float4*)&sWs[f*A_];
    const float4 w1 = *(const float4*)&sWs[f*A_+4];
    const float wa[8] = {w0.x,w0.y,w0.z,w0.w,w1.x,w1.y,w1.z,w1.w};
    #pragma unroll
    for (int a=0;a<A_;++a) t0[a] = fmaf(d0[f], wa[a], t0[a]);
  }

  float o[NF_];
  #pragma unroll
  for (int n=0;n<NF_;++n) o[n]=sbo[n];
  #pragma unroll
  for (int a=0;a<A_;++a){
    const float e = __expf(-t0[a]*t0[a]);   // mask folded into final scale
    const float4 q0 = *(const float4*)&sM[a*NF_];
    const float4 q1 = *(const float4*)&sM[a*NF_+4];
    const float4 q2 = *(const float4*)&sM[a*NF_+8];
    const float4 q3 = *(const float4*)&sM[a*NF_+12];
    const float ma[16] = {q0.x,q0.y,q0.z,q0.w, q1.x,q1.y,q1.z,q1.w,
                          q2.x,q2.y,q2.z,q2.w, q3.x,q3.y,q3.z,q3.w};
    #pragma unroll
    for (int n=0;n<NF_;++n) o[n] = fmaf(e, ma[n], o[n]);
  }

  float4* ob = (float4*)(out + (voff+vl)*NF_);
  ob[0] = make_float4(o[0]*m,  o[1]*m,  o[2]*m,  o[3]*m);
  ob[1] = make_float4(o[4]*m,  o[5]*m,  o[6]*m,  o[7]*m);
  ob[2] = make_float4(o[8]*m,  o[9]*m,  o[10]*m, o[11]*m);
  ob[3] = make_float4(o[12]*m, o[13]*m, o[14]*m, o[15]*m);
}

__global__ __launch_bounds__(256, 4) void k_out(
    const void* __restrict__ data, const int* __restrict__ nv,
    const void* __restrict__ Wflr, const void* __restrict__ bflr,
    const void* __restrict__ Ws, const void* __restrict__ bs,
    const void* __restrict__ Wout, const void* __restrict__ bout,
    const float* __restrict__ partial, float* __restrict__ out)
{
  if (detect_bf16(data))
    out_body<true >(data, nv, Wflr, bflr, Ws, bs, Wout, bout, partial, out);
  else
    out_body<false>(data, nv, Wflr, bflr, Ws, bs, Wout, bout, partial, out);
}

extern "C" void kernel_launch(void* const* d_in, const int* in_sizes, int n_in,
                              void* d_out, int out_size, void* d_ws, size_t ws_size,
                              hipStream_t stream) {
  const void* data = d_in[0];
  const int*  nv   = (const int*)d_in[1];
  const void* Wflr = d_in[2];
  const void* bflr = d_in[3];
  const void* Ws   = d_in[4];
  const void* bs   = d_in[5];
  const void* Wout = d_in[6];
  const void* bout = d_in[7];
  float* out = (float*)d_out;
  float* partial = (float*)d_ws;   // 512*136*4 = 278528 B, fully overwritten by k_agg

  hipLaunchKernelGGL(k_agg, dim3(B_*SPLIT1), dim3(256), 0, stream,
                     data, nv, Ws, bs, partial);
  hipLaunchKernelGGL(k_out, dim3(B_*SPLIT2), dim3(256), 0, stream,
                     data, nv, Wflr, bflr, Ws, bs, Wout, bout, partial, out);
}

// Round 6
// 96.598 us; speedup vs baseline: 1.2666x; 1.0299x over previous
//
#include <hip/hip_runtime.h>

// GarNet: B=64 V=4096 F=16 A=8 P=16 NF=16. Inputs f32 (R2-confirmed), output f32.
// R5 lesson: G[128]-per-thread costs ~200 VGPR -> low occupancy + giant unroll
// body. This round k_agg uses ownership decomposition: phase 1 computes e[v,a]
// into LDS (with d[v,f]); phase 2 each thread owns one (a, f-quad) cell of the
// 8x16 G matrix and accumulates over a 32-vertex chunk straight from LDS.
// ~50 VGPR/thread, no cross-lane shuffles anywhere.
//
//   G[b,a,f]=sum_v ew*d, E=sum_v ew ; agg=(Wflr^T G + bflr E)/V ; M=agg*Wout
//   out[v,n]=mask*(sum_a ew[v,a]*M[a,n]+bout[n])

#define B_ 64
#define V_ 4096
#define F_ 16
#define A_ 8
#define P_ 16
#define NF_ 16
#define SPLIT1 8              // k_agg: 8 blocks/batch -> 512 blocks (2/CU)
#define SPLIT2 16             // k_out: 16 blocks/batch -> 1024 blocks (4/CU)
#define GE_ (A_*F_ + A_)      // 136 partials per k_agg block
#define ESTR 12               // e_lds row stride (16B-aligned writes, 2-way banks)
#define DSTR 20               // d_lds row stride (16B-aligned b128, 2-way banks)

typedef unsigned int uint32;
typedef unsigned short u16;

__device__ __forceinline__ float bflo(uint32 u){ union{uint32 i;float f;}x; x.i=u<<16; return x.f; }
__device__ __forceinline__ float bfhi(uint32 u){ union{uint32 i;float f;}x; x.i=u&0xffff0000u; return x.f; }

// dtype probe (R2: votes f32 on this harness; kept as cheap insurance)
__device__ __forceinline__ bool detect_bf16(const void* data){
  const uint32* w = (const uint32*)data;
  int c = 0;
  #pragma unroll
  for (int i=0;i<16;++i){
    uint32 e = (w[i]>>7) & 0xffu;
    c += (e>=100u && e<=135u) ? 1 : 0;
  }
  return c >= 11;
}

template<bool BF16>
__device__ __forceinline__ float ldw(const void* p, int i){
  return BF16 ? bflo((uint32)((const u16*)p)[i]) : ((const float*)p)[i];
}

template<bool BF16>
__device__ __forceinline__ void load_vertex(const void* base, size_t v, float* d){
  if (BF16){
    const uint4* p = (const uint4*)((const u16*)base + v*F_);
    uint4 r0=p[0], r1=p[1];
    d[0]=bflo(r0.x); d[1]=bfhi(r0.x); d[2]=bflo(r0.y); d[3]=bfhi(r0.y);
    d[4]=bflo(r0.z); d[5]=bfhi(r0.z); d[6]=bflo(r0.w); d[7]=bfhi(r0.w);
    d[8]=bflo(r1.x); d[9]=bfhi(r1.x); d[10]=bflo(r1.y); d[11]=bfhi(r1.y);
    d[12]=bflo(r1.z); d[13]=bfhi(r1.z); d[14]=bflo(r1.w); d[15]=bfhi(r1.w);
  } else {
    const float4* p = (const float4*)((const float*)base + v*F_);
    float4 a=p[0], b=p[1], c=p[2], e=p[3];
    d[0]=a.x; d[1]=a.y; d[2]=a.z; d[3]=a.w;
    d[4]=b.x; d[5]=b.y; d[6]=b.z; d[7]=b.w;
    d[8]=c.x; d[9]=c.y; d[10]=c.z; d[11]=c.w;
    d[12]=e.x; d[13]=e.y; d[14]=e.z; d[15]=e.w;
  }
}

// ---------------- Kernel A: G[a,f], E[a] per (batch, split) ----------------
template<bool BF16>
__device__ __forceinline__ void agg_body(
    const void* __restrict__ data, const int* __restrict__ nv,
    const void* __restrict__ Ws, const void* __restrict__ bs,
    float* __restrict__ partial)
{
  __shared__ __align__(16) float sWs[F_*A_];
  __shared__ float sbs[A_];
  __shared__ __align__(16) float e_lds[256*ESTR];   // 12 KB, e[v][a] (stride 12)
  __shared__ __align__(16) float d_lds[256*DSTR];   // 20 KB, d[v][f] (stride 20)
  __shared__ __align__(16) float gred[8*32*4];      // 4 KB, [chunk][group]x4
  __shared__ float ered2[16*8];                     // E partial stage

  const int tid = threadIdx.x;
  if (tid < F_*A_) sWs[tid] = ldw<BF16>(Ws, tid);
  if (tid < A_)    sbs[tid] = ldw<BF16>(bs, tid);
  const int b = blockIdx.x >> 3;
  const int s = blockIdx.x & 7;
  const int nvb = nv[b];
  __syncthreads();

  const int vbase = s*(V_/SPLIT1);       // 512 vertices per block, 2 tiles of 256
  const size_t voff = (size_t)b*V_ + vbase;

  // ownership: group g = (a, f-quad), chunk c = 32-vertex slice
  const int g  = tid & 31;
  const int c  = tid >> 5;
  const int ga = g >> 2;                 // aggregator this thread accumulates
  const int gf = g & 3;                  // f-quad this thread accumulates

  float acc0=0.f, acc1=0.f, acc2=0.f, acc3=0.f;   // G[ga][gf*4..+3]
  float E[A_];
  #pragma unroll
  for (int a=0;a<A_;++a) E[a]=0.f;

  #pragma unroll
  for (int T=0; T<2; ++T) {
    // ---- phase 1: my vertex -> e[8], stash e,d in LDS ----
    const int vl = T*256 + tid;
    float d0[16];
    load_vertex<BF16>(data, voff+vl, d0);
    const float m = (vbase+vl < nvb) ? 1.f : 0.f;

    float t0[A_];
    #pragma unroll
    for (int a=0;a<A_;++a) t0[a]=sbs[a];
    #pragma unroll
    for (int f=0; f<F_; ++f){
      const float4 w0 = *(const float4*)&sWs[f*A_];
      const float4 w1 = *(const float4*)&sWs[f*A_+4];
      const float wa[8] = {w0.x,w0.y,w0.z,w0.w,w1.x,w1.y,w1.z,w1.w};
      #pragma unroll
      for (int a=0;a<A_;++a) t0[a] = fmaf(d0[f], wa[a], t0[a]);
    }
    float e0[A_];
    #pragma unroll
    for (int a=0;a<A_;++a){
      e0[a] = m*__expf(-t0[a]*t0[a]);
      E[a] += e0[a];
    }
    float* er = &e_lds[tid*ESTR];
    *(float4*)(er)   = make_float4(e0[0],e0[1],e0[2],e0[3]);
    *(float4*)(er+4) = make_float4(e0[4],e0[5],e0[6],e0[7]);
    float* dr = &d_lds[tid*DSTR];
    *(float4*)(dr)    = make_float4(d0[0],d0[1],d0[2],d0[3]);
    *(float4*)(dr+4)  = make_float4(d0[4],d0[5],d0[6],d0[7]);
    *(float4*)(dr+8)  = make_float4(d0[8],d0[9],d0[10],d0[11]);
    *(float4*)(dr+12) = make_float4(d0[12],d0[13],d0[14],d0[15]);
    __syncthreads();

    // ---- phase 2: accumulate my (a,f-quad) over my 32-vertex chunk ----
    const float* ep = &e_lds[(c<<5)*ESTR + ga];
    const float* dp = &d_lds[(c<<5)*DSTR + gf*4];
    #pragma unroll 8
    for (int i=0;i<32;++i){
      const float e  = ep[i*ESTR];                 // broadcast-ish, <=2-way
      const float4 dv = *(const float4*)(dp + i*DSTR);
      acc0 = fmaf(e, dv.x, acc0);
      acc1 = fmaf(e, dv.y, acc1);
      acc2 = fmaf(e, dv.z, acc2);
      acc3 = fmaf(e, dv.w, acc3);
    }
    __syncthreads();                               // LDS reused next tile
  }

  // ---- reductions ----
  // G: 8 chunks per group
  *(float4*)&gred[(c*32+g)*4] = make_float4(acc0,acc1,acc2,acc3);
  // E rows (reuse e_lds, safe after the sync above)
  float* er = &e_lds[tid*ESTR];
  *(float4*)(er)   = make_float4(E[0],E[1],E[2],E[3]);
  *(float4*)(er+4) = make_float4(E[4],E[5],E[6],E[7]);
  __syncthreads();

  if (tid < 128){                        // G: (group, f-in-quad) -> sum 8 chunks
    const int gg = tid >> 2, fi = tid & 3;
    float sum = 0.f;
    #pragma unroll
    for (int k=0;k<8;++k) sum += gred[(k*32+gg)*4 + fi];
    partial[(size_t)blockIdx.x*GE_ + (gg>>2)*F_ + (gg&3)*4 + fi] = sum;
  } else {                               // E stage 1: 128 threads sum 16 rows each
    const int t2 = tid - 128;
    const int q = t2 >> 3, a = t2 & 7;
    float sum = 0.f;
    #pragma unroll
    for (int i=0;i<16;++i) sum += e_lds[(q*16+i)*ESTR + a];
    ered2[q*8 + a] = sum;
  }
  __syncthreads();
  if (tid < A_){                         // E stage 2
    float sum = 0.f;
    #pragma unroll
    for (int q=0;q<16;++q) sum += ered2[q*8 + tid];
    partial[(size_t)blockIdx.x*GE_ + A_*F_ + tid] = sum;
  }
}

__global__ __launch_bounds__(256, 4) void k_agg(
    const void* __restrict__ data, const int* __restrict__ nv,
    const void* __restrict__ Ws, const void* __restrict__ bs,
    float* __restrict__ partial)
{
  if (detect_bf16(data)) agg_body<true >(data, nv, Ws, bs, partial);
  else                   agg_body<false>(data, nv, Ws, bs, partial);
}

// ------------- Kernel B: agg->M per batch, recompute ew, emit f32 out -------------
template<bool BF16>
__device__ __forceinline__ void out_body(
    const void* __restrict__ data, const int* __restrict__ nv,
    const void* __restrict__ Wflr, const void* __restrict__ bflr,
    const void* __restrict__ Ws, const void* __restrict__ bs,
    const void* __restrict__ Wout, const void* __restrict__ bout,
    const float* __restrict__ partial, float* __restrict__ out)
{
  __shared__ __align__(16) float sWs[F_*A_];
  __shared__ __align__(16) float sWf[F_*P_];
  __shared__ float sbf[P_], sbs[A_], sbo[NF_];
  __shared__ float sGE[GE_];
  __shared__ float sagg[A_*P_];
  __shared__ __align__(16) float sM[A_*NF_];

  const int tid = threadIdx.x;
  const int b = blockIdx.x >> 4;
  const int s = blockIdx.x & 15;

  if (tid < F_*P_) sWf[tid] = ldw<BF16>(Wflr, tid);
  if (tid < F_*A_) sWs[tid] = ldw<BF16>(Ws, tid);
  if (tid < P_)    sbf[tid] = ldw<BF16>(bflr, tid);
  if (tid < A_)    sbs[tid] = ldw<BF16>(bs, tid);
  if (tid < NF_)   sbo[tid] = ldw<BF16>(bout, tid);
  if (tid < GE_) {
    const float* pp = partial + (size_t)(b*SPLIT1)*GE_ + tid;
    float v = 0.f;
    #pragma unroll
    for (int k=0;k<SPLIT1;++k) v += pp[(size_t)k*GE_];
    sGE[tid] = v;
  }
  const int nvb = nv[b];
  __syncthreads();

  if (tid < A_*P_) {                     // agg[a,p]
    const int a = tid >> 4, p = tid & 15;
    float acc = sGE[A_*F_ + a] * sbf[p];
    #pragma unroll
    for (int f=0;f<F_;++f) acc = fmaf(sGE[a*F_+f], sWf[f*P_+p], acc);
    sagg[tid] = acc * (1.0f/(float)V_);
  }
  __syncthreads();
  if (tid < A_*NF_) {                    // M[a,n]
    const int a = tid >> 4, n = tid & 15;
    float m = 0.f;
    #pragma unroll
    for (int p=0;p<P_;++p)
      m = fmaf(sagg[a*P_+p], ldw<BF16>(Wout, (a*P_+p)*NF_+n), m);
    sM[tid] = m;
  }
  __syncthreads();

  // 1 vertex per thread
  const int vbase = s*(V_/SPLIT2);       // 256 vertices per block
  const int vl = tid;
  const size_t voff = (size_t)b*V_ + vbase;
  float d0[16];
  load_vertex<BF16>(data, voff+vl, d0);
  const float m = (vbase+vl < nvb) ? 1.f : 0.f;

  float t0[A_];
  #pragma unroll
  for (int a=0;a<A_;++a) t0[a]=sbs[a];
  #pragma unroll
  for (int f=0; f<F_; ++f){
    const float4 w0 = *(const float4*)&sWs[f*A_];
    const float4 w1 = *(const float4*)&sWs[f*A_+4];
    const float wa[8] = {w0.x,w0.y,w0.z,w0.w,w1.x,w1.y,w1.z,w1.w};
    #pragma unroll
    for (int a=0;a<A_;++a) t0[a] = fmaf(d0[f], wa[a], t0[a]);
  }

  float o[NF_];
  #pragma unroll
  for (int n=0;n<NF_;++n) o[n]=sbo[n];
  #pragma unroll
  for (int a=0;a<A_;++a){
    const float e = __expf(-t0[a]*t0[a]);   // mask folded into final scale
    const float4 q0 = *(const float4*)&sM[a*NF_];
    const float4 q1 = *(const float4*)&sM[a*NF_+4];
    const float4 q2 = *(const float4*)&sM[a*NF_+8];
    const float4 q3 = *(const float4*)&sM[a*NF_+12];
    const float ma[16] = {q0.x,q0.y,q0.z,q0.w, q1.x,q1.y,q1.z,q1.w,
                          q2.x,q2.y,q2.z,q2.w, q3.x,q3.y,q3.z,q3.w};
    #pragma unroll
    for (int n=0;n<NF_;++n) o[n] = fmaf(e, ma[n], o[n]);
  }

  float4* ob = (float4*)(out + (voff+vl)*NF_);
  ob[0] = make_float4(o[0]*m,  o[1]*m,  o[2]*m,  o[3]*m);
  ob[1] = make_float4(o[4]*m,  o[5]*m,  o[6]*m,  o[7]*m);
  ob[2] = make_float4(o[8]*m,  o[9]*m,  o[10]*m, o[11]*m);
  ob[3] = make_float4(o[12]*m, o[13]*m, o[14]*m, o[15]*m);
}

__global__ __launch_bounds__(256, 4) void k_out(
    const void* __restrict__ data, const int* __restrict__ nv,
    const void* __restrict__ Wflr, const void* __restrict__ bflr,
    const void* __restrict__ Ws, const void* __restrict__ bs,
    const void* __restrict__ Wout, const void* __restrict__ bout,
    const float* __restrict__ partial, float* __restrict__ out)
{
  if (detect_bf16(data))
    out_body<true >(data, nv, Wflr, bflr, Ws, bs, Wout, bout, partial, out);
  else
    out_body<false>(data, nv, Wflr, bflr, Ws, bs, Wout, bout, partial, out);
}

extern "C" void kernel_launch(void* const* d_in, const int* in_sizes, int n_in,
                              void* d_out, int out_size, void* d_ws, size_t ws_size,
                              hipStream_t stream) {
  const void* data = d_in[0];
  const int*  nv   = (const int*)d_in[1];
  const void* Wflr = d_in[2];
  const void* bflr = d_in[3];
  const void* Ws   = d_in[4];
  const void* bs   = d_in[5];
  const void* Wout = d_in[6];
  const void* bout = d_in[7];
  float* out = (float*)d_out;
  float* partial = (float*)d_ws;   // 512*136*4 = 278528 B, fully overwritten by k_agg

  hipLaunchKernelGGL(k_agg, dim3(B_*SPLIT1), dim3(256), 0, stream,
                     data, nv, Ws, bs, partial);
  hipLaunchKernelGGL(k_out, dim3(B_*SPLIT2), dim3(256), 0, stream,
                     data, nv, Wflr, bflr, Ws, bs, Wout, bout, partial, out);
}

// Round 7
// 94.276 us; speedup vs baseline: 1.2978x; 1.0246x over previous
//
#include <hip/hip_runtime.h>

// GarNet: B=64 V=4096 F=16 A=8 P=16 NF=16. Inputs f32 (R2-confirmed), output f32.
// R6 lesson: ownership-decomposed k_agg works; k_out still redundantly re-reads
// data and recomputes dist/exp. R7: k_agg caches masked e[v][8] as u16 fixed-point
// (abs err 7.6e-6) in ws; k_out becomes a streaming kernel (read e, write out),
// mask derived from nv, bias-only masking since cached e is pre-masked.
//
//   G[b,a,f]=sum_v ew*d, E=sum_v ew ; agg=(Wflr^T G + bflr E)/V ; M=agg*Wout
//   out[v,n]= mask*bout[n] + sum_a ew[v,a]*M[a,n]      (ew==0 for masked v)

#define B_ 64
#define V_ 4096
#define F_ 16
#define A_ 8
#define P_ 16
#define NF_ 16
#define SPLIT1 8              // k_agg: 8 blocks/batch -> 512 blocks
#define SPLIT2 16             // k_out: 16 blocks/batch -> 1024 blocks
#define GE_ (A_*F_ + A_)      // 136 partials per k_agg block
#define ESTR 12               // e_lds row stride (16B-aligned writes, 2-way banks)
#define DSTR 20               // d_lds row stride (16B-aligned b128, 2-way banks)

typedef unsigned int uint32;
typedef unsigned short u16;

__device__ __forceinline__ float bflo(uint32 u){ union{uint32 i;float f;}x; x.i=u<<16; return x.f; }
__device__ __forceinline__ float bfhi(uint32 u){ union{uint32 i;float f;}x; x.i=u&0xffff0000u; return x.f; }

// dtype probe (R2: votes f32 on this harness; kept as cheap insurance)
__device__ __forceinline__ bool detect_bf16(const void* data){
  const uint32* w = (const uint32*)data;
  int c = 0;
  #pragma unroll
  for (int i=0;i<16;++i){
    uint32 e = (w[i]>>7) & 0xffu;
    c += (e>=100u && e<=135u) ? 1 : 0;
  }
  return c >= 11;
}

template<bool BF16>
__device__ __forceinline__ float ldw(const void* p, int i){
  return BF16 ? bflo((uint32)((const u16*)p)[i]) : ((const float*)p)[i];
}

template<bool BF16>
__device__ __forceinline__ void load_vertex(const void* base, size_t v, float* d){
  if (BF16){
    const uint4* p = (const uint4*)((const u16*)base + v*F_);
    uint4 r0=p[0], r1=p[1];
    d[0]=bflo(r0.x); d[1]=bfhi(r0.x); d[2]=bflo(r0.y); d[3]=bfhi(r0.y);
    d[4]=bflo(r0.z); d[5]=bfhi(r0.z); d[6]=bflo(r0.w); d[7]=bfhi(r0.w);
    d[8]=bflo(r1.x); d[9]=bfhi(r1.x); d[10]=bflo(r1.y); d[11]=bfhi(r1.y);
    d[12]=bflo(r1.z); d[13]=bfhi(r1.z); d[14]=bflo(r1.w); d[15]=bfhi(r1.w);
  } else {
    const float4* p = (const float4*)((const float*)base + v*F_);
    float4 a=p[0], b=p[1], c=p[2], e=p[3];
    d[0]=a.x; d[1]=a.y; d[2]=a.z; d[3]=a.w;
    d[4]=b.x; d[5]=b.y; d[6]=b.z; d[7]=b.w;
    d[8]=c.x; d[9]=c.y; d[10]=c.z; d[11]=c.w;
    d[12]=e.x; d[13]=e.y; d[14]=e.z; d[15]=e.w;
  }
}

// ---------------- Kernel A: G[a,f], E[a] per (batch, split); cache e ----------------
template<bool BF16>
__device__ __forceinline__ void agg_body(
    const void* __restrict__ data, const int* __restrict__ nv,
    const void* __restrict__ Ws, const void* __restrict__ bs,
    float* __restrict__ partial, uint4* __restrict__ ecache)
{
  __shared__ __align__(16) float sWs[F_*A_];
  __shared__ float sbs[A_];
  __shared__ __align__(16) float e_lds[256*ESTR];   // 12 KB, e[v][a] (stride 12)
  __shared__ __align__(16) float d_lds[256*DSTR];   // 20 KB, d[v][f] (stride 20)
  __shared__ __align__(16) float gred[8*32*4];      // 4 KB, [chunk][group]x4
  __shared__ float ered2[16*8];                     // E partial stage

  const int tid = threadIdx.x;
  if (tid < F_*A_) sWs[tid] = ldw<BF16>(Ws, tid);
  if (tid < A_)    sbs[tid] = ldw<BF16>(bs, tid);
  const int b = blockIdx.x >> 3;
  const int s = blockIdx.x & 7;
  const int nvb = nv[b];
  __syncthreads();

  const int vbase = s*(V_/SPLIT1);       // 512 vertices per block, 2 tiles of 256
  const size_t voff = (size_t)b*V_ + vbase;

  // ownership: group g = (a, f-quad), chunk c = 32-vertex slice
  const int g  = tid & 31;
  const int c  = tid >> 5;
  const int ga = g >> 2;
  const int gf = g & 3;

  float acc0=0.f, acc1=0.f, acc2=0.f, acc3=0.f;   // G[ga][gf*4..+3]
  float E[A_];
  #pragma unroll
  for (int a=0;a<A_;++a) E[a]=0.f;

  #pragma unroll
  for (int T=0; T<2; ++T) {
    // ---- phase 1: my vertex -> e[8], stash e,d in LDS + e-cache to ws ----
    const int vl = T*256 + tid;
    float d0[16];
    load_vertex<BF16>(data, voff+vl, d0);
    const float m = (vbase+vl < nvb) ? 1.f : 0.f;

    float t0[A_];
    #pragma unroll
    for (int a=0;a<A_;++a) t0[a]=sbs[a];
    #pragma unroll
    for (int f=0; f<F_; ++f){
      const float4 w0 = *(const float4*)&sWs[f*A_];
      const float4 w1 = *(const float4*)&sWs[f*A_+4];
      const float wa[8] = {w0.x,w0.y,w0.z,w0.w,w1.x,w1.y,w1.z,w1.w};
      #pragma unroll
      for (int a=0;a<A_;++a) t0[a] = fmaf(d0[f], wa[a], t0[a]);
    }
    float e0[A_];
    #pragma unroll
    for (int a=0;a<A_;++a){
      e0[a] = m*__expf(-t0[a]*t0[a]);
      E[a] += e0[a];
    }
    // e-cache: u16 fixed-point, e in [0,1] -> abs err <= 0.5/65535
    {
      const uint32 q0 = __float2uint_rn(e0[0]*65535.f) | (__float2uint_rn(e0[1]*65535.f)<<16);
      const uint32 q1 = __float2uint_rn(e0[2]*65535.f) | (__float2uint_rn(e0[3]*65535.f)<<16);
      const uint32 q2 = __float2uint_rn(e0[4]*65535.f) | (__float2uint_rn(e0[5]*65535.f)<<16);
      const uint32 q3 = __float2uint_rn(e0[6]*65535.f) | (__float2uint_rn(e0[7]*65535.f)<<16);
      ecache[voff+vl] = make_uint4(q0,q1,q2,q3);
    }
    float* er = &e_lds[tid*ESTR];
    *(float4*)(er)   = make_float4(e0[0],e0[1],e0[2],e0[3]);
    *(float4*)(er+4) = make_float4(e0[4],e0[5],e0[6],e0[7]);
    float* dr = &d_lds[tid*DSTR];
    *(float4*)(dr)    = make_float4(d0[0],d0[1],d0[2],d0[3]);
    *(float4*)(dr+4)  = make_float4(d0[4],d0[5],d0[6],d0[7]);
    *(float4*)(dr+8)  = make_float4(d0[8],d0[9],d0[10],d0[11]);
    *(float4*)(dr+12) = make_float4(d0[12],d0[13],d0[14],d0[15]);
    __syncthreads();

    // ---- phase 2: accumulate my (a,f-quad) over my 32-vertex chunk ----
    const float* ep = &e_lds[(c<<5)*ESTR + ga];
    const float* dp = &d_lds[(c<<5)*DSTR + gf*4];
    #pragma unroll 8
    for (int i=0;i<32;++i){
      const float e  = ep[i*ESTR];
      const float4 dv = *(const float4*)(dp + i*DSTR);
      acc0 = fmaf(e, dv.x, acc0);
      acc1 = fmaf(e, dv.y, acc1);
      acc2 = fmaf(e, dv.z, acc2);
      acc3 = fmaf(e, dv.w, acc3);
    }
    __syncthreads();                               // LDS reused next tile
  }

  // ---- reductions ----
  *(float4*)&gred[(c*32+g)*4] = make_float4(acc0,acc1,acc2,acc3);
  float* er = &e_lds[tid*ESTR];
  *(float4*)(er)   = make_float4(E[0],E[1],E[2],E[3]);
  *(float4*)(er+4) = make_float4(E[4],E[5],E[6],E[7]);
  __syncthreads();

  if (tid < 128){                        // G: (group, f-in-quad) -> sum 8 chunks
    const int gg = tid >> 2, fi = tid & 3;
    float sum = 0.f;
    #pragma unroll
    for (int k=0;k<8;++k) sum += gred[(k*32+gg)*4 + fi];
    partial[(size_t)blockIdx.x*GE_ + (gg>>2)*F_ + (gg&3)*4 + fi] = sum;
  } else {                               // E stage 1
    const int t2 = tid - 128;
    const int q = t2 >> 3, a = t2 & 7;
    float sum = 0.f;
    #pragma unroll
    for (int i=0;i<16;++i) sum += e_lds[(q*16+i)*ESTR + a];
    ered2[q*8 + a] = sum;
  }
  __syncthreads();
  if (tid < A_){                         // E stage 2
    float sum = 0.f;
    #pragma unroll
    for (int q=0;q<16;++q) sum += ered2[q*8 + tid];
    partial[(size_t)blockIdx.x*GE_ + A_*F_ + tid] = sum;
  }
}

__global__ __launch_bounds__(256, 4) void k_agg(
    const void* __restrict__ data, const int* __restrict__ nv,
    const void* __restrict__ Ws, const void* __restrict__ bs,
    float* __restrict__ partial, uint4* __restrict__ ecache)
{
  if (detect_bf16(data)) agg_body<true >(data, nv, Ws, bs, partial, ecache);
  else                   agg_body<false>(data, nv, Ws, bs, partial, ecache);
}

// ------------- Kernel B: agg->M per batch, read e-cache, emit f32 out -------------
template<bool BF16>
__device__ __forceinline__ void out_body(
    const int* __restrict__ nv,
    const void* __restrict__ Wflr, const void* __restrict__ bflr,
    const void* __restrict__ Wout, const void* __restrict__ bout,
    const float* __restrict__ partial, const uint4* __restrict__ ecache,
    float* __restrict__ out)
{
  __shared__ __align__(16) float sWf[F_*P_];
  __shared__ __align__(16) float sWo[A_*P_*NF_];   // 8 KB staged Wout
  __shared__ float sbf[P_], sbo[NF_];
  __shared__ float sGE[GE_];
  __shared__ float sagg[A_*P_];
  __shared__ __align__(16) float sM[A_*NF_];

  const int tid = threadIdx.x;
  const int b = blockIdx.x >> 4;
  const int s = blockIdx.x & 15;

  sWf[tid] = ldw<BF16>(Wflr, tid);                 // F*P == 256
  #pragma unroll
  for (int j=0;j<8;++j)                            // 2048 floats, coalesced-ish
    sWo[tid*8+j] = ldw<BF16>(Wout, tid*8+j);
  if (tid < P_)  sbf[tid] = ldw<BF16>(bflr, tid);
  if (tid < NF_) sbo[tid] = ldw<BF16>(bout, tid);
  if (tid < GE_) {
    const float* pp = partial + (size_t)(b*SPLIT1)*GE_ + tid;
    float v = 0.f;
    #pragma unroll
    for (int k=0;k<SPLIT1;++k) v += pp[(size_t)k*GE_];
    sGE[tid] = v;
  }
  const int nvb = nv[b];
  __syncthreads();

  if (tid < A_*P_) {                     // agg[a,p]
    const int a = tid >> 4, p = tid & 15;
    float acc = sGE[A_*F_ + a] * sbf[p];
    #pragma unroll
    for (int f=0;f<F_;++f) acc = fmaf(sGE[a*F_+f], sWf[f*P_+p], acc);
    sagg[tid] = acc * (1.0f/(float)V_);
  }
  __syncthreads();
  if (tid < A_*NF_) {                    // M[a,n]
    const int a = tid >> 4, n = tid & 15;
    float m = 0.f;
    #pragma unroll
    for (int p=0;p<P_;++p)
      m = fmaf(sagg[a*P_+p], sWo[(a*P_+p)*NF_+n], m);
    sM[tid] = m;
  }
  __syncthreads();

  // 1 vertex per thread: read cached e, emit out
  const int vbase = s*(V_/SPLIT2);       // 256 vertices per block
  const int vl = tid;
  const size_t v = (size_t)b*V_ + vbase + vl;
  const float m = (vbase+vl < nvb) ? 1.f : 0.f;

  const uint4 eu = ecache[v];
  const float k16 = 1.0f/65535.f;
  float e0[A_];
  e0[0] = (float)(eu.x & 0xffffu)*k16;  e0[1] = (float)(eu.x >> 16)*k16;
  e0[2] = (float)(eu.y & 0xffffu)*k16;  e0[3] = (float)(eu.y >> 16)*k16;
  e0[4] = (float)(eu.z & 0xffffu)*k16;  e0[5] = (float)(eu.z >> 16)*k16;
  e0[6] = (float)(eu.w & 0xffffu)*k16;  e0[7] = (float)(eu.w >> 16)*k16;

  float o[NF_];
  #pragma unroll
  for (int n=0;n<NF_;++n) o[n] = m*sbo[n];         // e pre-masked; only bias needs m
  #pragma unroll
  for (int a=0;a<A_;++a){
    const float e = e0[a];
    const float4 q0 = *(const float4*)&sM[a*NF_];
    const float4 q1 = *(const float4*)&sM[a*NF_+4];
    const float4 q2 = *(const float4*)&sM[a*NF_+8];
    const float4 q3 = *(const float4*)&sM[a*NF_+12];
    const float ma[16] = {q0.x,q0.y,q0.z,q0.w, q1.x,q1.y,q1.z,q1.w,
                          q2.x,q2.y,q2.z,q2.w, q3.x,q3.y,q3.z,q3.w};
    #pragma unroll
    for (int n=0;n<NF_;++n) o[n] = fmaf(e, ma[n], o[n]);
  }

  float4* ob = (float4*)(out + v*NF_);
  ob[0] = make_float4(o[0],  o[1],  o[2],  o[3]);
  ob[1] = make_float4(o[4],  o[5],  o[6],  o[7]);
  ob[2] = make_float4(o[8],  o[9],  o[10], o[11]);
  ob[3] = make_float4(o[12], o[13], o[14], o[15]);
}

__global__ __launch_bounds__(256, 4) void k_out(
    const void* __restrict__ data, const int* __restrict__ nv,
    const void* __restrict__ Wflr, const void* __restrict__ bflr,
    const void* __restrict__ Wout, const void* __restrict__ bout,
    const float* __restrict__ partial, const uint4* __restrict__ ecache,
    float* __restrict__ out)
{
  if (detect_bf16(data))
    out_body<true >(nv, Wflr, bflr, Wout, bout, partial, ecache, out);
  else
    out_body<false>(nv, Wflr, bflr, Wout, bout, partial, ecache, out);
}

extern "C" void kernel_launch(void* const* d_in, const int* in_sizes, int n_in,
                              void* d_out, int out_size, void* d_ws, size_t ws_size,
                              hipStream_t stream) {
  const void* data = d_in[0];
  const int*  nv   = (const int*)d_in[1];
  const void* Wflr = d_in[2];
  const void* bflr = d_in[3];
  const void* Ws   = d_in[4];
  const void* bs   = d_in[5];
  const void* Wout = d_in[6];
  const void* bout = d_in[7];
  float* out = (float*)d_out;
  float* partial = (float*)d_ws;                   // 512*136*4 = 278528 B
  uint4* ecache  = (uint4*)((char*)d_ws + 278528); // 64*4096*16 B = 4 MiB
  // both regions fully overwritten by k_agg each launch (no init needed)

  hipLaunchKernelGGL(k_agg, dim3(B_*SPLIT1), dim3(256), 0, stream,
                     data, nv, Ws, bs, partial, ecache);
  hipLaunchKernelGGL(k_out, dim3(B_*SPLIT2), dim3(256), 0, stream,
                     data, nv, Wflr, bflr, Wout, bout, partial, ecache, out);
}